// Round 3
// baseline (128.453 us; speedup 1.0000x reference)
//
#include <hip/hip_runtime.h>
#include <hip/hip_bf16.h>

typedef __bf16    bf16x8  __attribute__((ext_vector_type(8)));
typedef __bf16    bf16x4  __attribute__((ext_vector_type(4)));
typedef _Float16  half8   __attribute__((ext_vector_type(8)));
typedef _Float16  half4   __attribute__((ext_vector_type(4)));
typedef _Float16  half2   __attribute__((ext_vector_type(2)));
typedef float     floatx4 __attribute__((ext_vector_type(4)));

constexpr int Bc  = 2;
constexpr int Hc  = 16;
constexpr int Lc  = 2048;
constexpr int Dc  = 64;
constexpr int BHn = Bc * Hc;     // 32
constexpr int BM  = 128;         // query rows per q-tile
constexpr int BN  = 128;         // keys per kv tile
constexpr int NQT = Lc / BM;     // 16 query tiles
constexpr int LDK = 72;          // K padded stride (bf16 elems) -> row = 144 B
constexpr int LDV = 136;         // V^T padded stride (f16 elems) -> row = 272 B
constexpr int LDQ = 68;          // Q staging stride (bf16) -> 256 rows fit one buffer
constexpr int KBYTES = BN * LDK * 2;            // 18432
constexpr int VBYTES = Dc * LDV * 2;            // 17408
constexpr int TILE_BYTES = KBYTES + VBYTES;     // 35840 (= LDS image of one tile)
constexpr int TILE_GRANS = TILE_BYTES / 16;     // 2240 granules of 16 B

static __device__ __forceinline__ half2 pack_f16(float a, float b) {
    return __builtin_bit_cast(half2, __builtin_amdgcn_cvt_pkrtz(a, b));
}

static __device__ __forceinline__ void dma16(const void* g, void* l) {
    __builtin_amdgcn_global_load_lds(
        (const __attribute__((address_space(1))) void*)g,
        (__attribute__((address_space(3))) void*)l, 16, 0, 0);
}

// ---- pre-pass: write K/V tiles in the exact padded LDS image ----
// kv layout: [bh][tile=16][ K: 128 rows x 144 B | V^T: 64 rows x 272 B ] = 35840 B/tile
// V^T value at [d][pcol] = V[key(pcol)][d]; pcol permutation within each 32-key group:
// k5 -> 8*((k5>>2)&3) + 4*(k5>>4) + (k5&3)  (makes PV A-frags b128-contiguous)
__global__ void prep(const float* __restrict__ kp, const float* __restrict__ vp,
                     char* __restrict__ kv) {
    const int bid = blockIdx.x, tid = threadIdx.x;
    if (bid < 1024) {
        // K part: 1024 blocks x 256 threads; 4 threads per K row (16 d each)
        const int R    = bid * 64 + (tid >> 2);   // global row: bh*2048 + key
        const int s    = tid & 3;
        const int bh   = R >> 11;
        const int key  = R & 2047;
        const int tile = key >> 7;
        const int krow = key & 127;
        const float* src = kp + (size_t)R * 64 + s * 16;
        char* dst = kv + (size_t)(bh * 16 + tile) * TILE_BYTES + krow * 144 + s * 32;
        #pragma unroll
        for (int h = 0; h < 2; ++h) {
            floatx4 a = *(const floatx4*)(src + h * 8);
            floatx4 b = *(const floatx4*)(src + h * 8 + 4);
            bf16x8 o;
            o[0] = (__bf16)a[0]; o[1] = (__bf16)a[1]; o[2] = (__bf16)a[2]; o[3] = (__bf16)a[3];
            o[4] = (__bf16)b[0]; o[5] = (__bf16)b[1]; o[6] = (__bf16)b[2]; o[7] = (__bf16)b[3];
            *(bf16x8*)(dst + h * 16) = o;
        }
    } else {
        // V part: 1024 blocks; block handles 64 keys (half a tile) x 64 d
        const int vb   = bid - 1024;
        const int bh   = vb >> 5, kt = vb & 31;
        const int key  = kt * 64 + (tid & 63);
        const int tile = kt >> 1;
        const int kwt  = (kt & 1) * 64 + (tid & 63);   // key within tile
        const int k5   = kwt & 31;
        const int pcol = (kwt & ~31) | (((k5 >> 2) & 3) * 8 + ((k5 >> 4) & 1) * 4 + (k5 & 3));
        const int d0   = (tid >> 6) * 16;
        const float* src = vp + ((size_t)bh * Lc + key) * Dc;
        _Float16* dst = (_Float16*)(kv + (size_t)(bh * 16 + tile) * TILE_BYTES + KBYTES);
        #pragma unroll
        for (int i = 0; i < 16; ++i) {
            const int d = d0 + i;
            dst[(size_t)d * LDV + pcol] = (_Float16)src[d];
        }
    }
}

// ---- main kernel: 256 persistent blocks (1/CU), 512 threads, dual q-tile kv sharing ----
// Waves 0-3 own q-tile A (qi), waves 4-7 own q-tile B (15-qi); each group is a 2x2
// (q-half x key-half) split. One kv staging serves both tiles: stagings/CU drop 17->9..16.
__global__ __launch_bounds__(512, 2)
void taylor_attn(const float* __restrict__ qp, const char* __restrict__ kv,
                 float* __restrict__ op)
{
    __shared__ __align__(16) char smem[2 * TILE_BYTES];   // 71680 B: buf0 | buf1

    const int tid  = threadIdx.x;
    const int wv   = tid >> 6;
    const int lane = tid & 63;
    const int lm   = lane & 15;
    const int quad = lane >> 4;
    const int grpB = wv >> 2;          // 0 = q-tile A, 1 = q-tile B
    const int wq   = (wv >> 1) & 1;    // q-half within group
    const int wk   = wv & 1;           // key-half within group

    const int bh    = (int)(blockIdx.x & 31);
    const int qpair = (int)(blockIdx.x >> 5);   // 0..7
    const int qiA   = qpair;
    const int qiB   = NQT - 1 - qpair;          // 8..15 (>= qiA always)
    const int jmaxW = grpB ? qiB : qiA;         // this wave's last tile
    const int q0w   = jmaxW * BM;               // this wave's q-tile base row
    const int jmaxB = qiB;                      // block loop bound

    const char* kvbh = kv + (size_t)bh * 16 * TILE_BYTES;

    // ---- issue Q global loads first (oldest vmem), then tile-0 DMA into buf0 ----
    floatx4 qv[8];
    const int r0 = tid >> 4, c4 = tid & 15;    // r0: 0..31
    {
        const float* qA = qp + ((size_t)bh * Lc + qiA * BM) * Dc;
        const float* qB = qp + ((size_t)bh * Lc + qiB * BM) * Dc;
        #pragma unroll
        for (int rep = 0; rep < 4; ++rep)
            qv[rep] = *(const floatx4*)(qA + (r0 + rep * 32) * Dc + c4 * 4);
        #pragma unroll
        for (int rep = 4; rep < 8; ++rep)
            qv[rep] = *(const floatx4*)(qB + (r0 + (rep - 4) * 32) * Dc + c4 * 4);
    }
    {
        const char* src = kvbh;          // tile 0
        #pragma unroll
        for (int rep = 0; rep < 4; ++rep)
            dma16(src + (rep * 512 + tid) * 16, smem + (rep * 512 + tid) * 16);
        if (tid < 192)
            dma16(src + (2048 + tid) * 16, smem + (2048 + tid) * 16);
    }

    // ---- stage Q (fp32 -> bf16) into buf1 (256 rows x LDQ), extract B-frags ----
    {
        __bf16* Qs = (__bf16*)(smem + TILE_BYTES);
        #pragma unroll
        for (int rep = 0; rep < 8; ++rep) {
            bf16x4 b;
            b[0] = (__bf16)qv[rep][0]; b[1] = (__bf16)qv[rep][1];
            b[2] = (__bf16)qv[rep][2]; b[3] = (__bf16)qv[rep][3];
            *(bf16x4*)&Qs[(r0 + rep * 32) * LDQ + c4 * 4] = b;
        }
    }
    asm volatile("s_waitcnt lgkmcnt(0)" ::: "memory");
    __builtin_amdgcn_s_barrier();

    bf16x8 qa[4][2];   // [strip][kf]; B-frag: n=lm (qrow), k=kf*32+quad*8+j
    {
        const __bf16* Qs = (const __bf16*)(smem + TILE_BYTES);
        #pragma unroll
        for (int st = 0; st < 4; ++st)
            #pragma unroll
            for (int kf = 0; kf < 2; ++kf)
                qa[st][kf] = *(const bf16x8*)&Qs[(128 * grpB + 64 * wq + 16 * st + lm) * LDQ + kf * 32 + quad * 8];
    }
    asm volatile("s_waitcnt lgkmcnt(0)" ::: "memory");
    __builtin_amdgcn_s_barrier();

    floatx4 oacc[4][4] = {};     // O^T partial (this wave's 64 keys): [strip][d-block]
    floatx4 zacc[4]    = {};     // z partial via ones-MFMA

    const half8 ones = {(_Float16)1.f, (_Float16)1.f, (_Float16)1.f, (_Float16)1.f,
                        (_Float16)1.f, (_Float16)1.f, (_Float16)1.f, (_Float16)1.f};
    const half2 c8  = {(_Float16)0.125f, (_Float16)0.125f};
    const half2 c1  = {(_Float16)1.f,    (_Float16)1.f};
    const half2 ch  = {(_Float16)0.5f,   (_Float16)0.5f};

    for (int j = 0; j <= jmaxB; ++j) {
        const int cur = j & 1;
        const __bf16*   Kc = (const __bf16*)(smem + cur * TILE_BYTES);
        const _Float16* Vc = (const _Float16*)(smem + cur * TILE_BYTES + KBYTES);

        // ---- issue next tile's DMA into the other buffer; counted vmcnt (never 0) ----
        if (j < jmaxB) {
            const char* src = kvbh + (size_t)(j + 1) * TILE_BYTES;
            char* dst = smem + (cur ^ 1) * TILE_BYTES;
            #pragma unroll
            for (int rep = 0; rep < 4; ++rep)
                dma16(src + (rep * 512 + tid) * 16, dst + (rep * 512 + tid) * 16);
            if (tid < 192)
                dma16(src + (2048 + tid) * 16, dst + (2048 + tid) * 16);
            if (wv < 3) asm volatile("s_waitcnt vmcnt(5)" ::: "memory");
            else        asm volatile("s_waitcnt vmcnt(4)" ::: "memory");
        } else {
            asm volatile("s_waitcnt vmcnt(0)" ::: "memory");
        }
        __builtin_amdgcn_s_barrier();

        const bool nm = (j == jmaxW);                  // this wave's diagonal tile
        // skip: past this wave's range, or fully-masked diagonal quadrant (wq=0,wk=1)
        const bool active = (j <= jmaxW) && !(nm && wk && !wq);
        if (active) {
            #pragma unroll
            for (int hf = 0; hf < 2; ++hf) {
                const int grp = 2 * wk + hf;           // 32-key group within the 128-tile

                // S^T = K * Q^T for key rows [32*grp, 32*grp+32), all 4 q-strips
                floatx4 sacc[4][2] = {};
                #pragma unroll
                for (int kb4 = 0; kb4 < 2; ++kb4) {
                    const int row0 = 16 * (4 * wk + 2 * hf + kb4);
                    #pragma unroll
                    for (int kf = 0; kf < 2; ++kf) {
                        bf16x8 ka = *(const bf16x8*)&Kc[(row0 + lm) * LDK + kf * 32 + quad * 8];
                        #pragma unroll
                        for (int st = 0; st < 4; ++st)
                            sacc[st][kb4] = __builtin_amdgcn_mfma_f32_16x16x32_bf16(ka, qa[st][kf], sacc[st][kb4], 0, 0, 0);
                    }
                }

                // packed-f16 Taylor + causal mask; wf = W B-frags (registers only)
                half8 wf[4];
                #pragma unroll
                for (int st = 0; st < 4; ++st) {
                    const int thr = q0w + 64 * wq + 16 * st + lm - j * BN;
                    half2 wh[2][2];
                    #pragma unroll
                    for (int kb4 = 0; kb4 < 2; ++kb4) {
                        half2 s01 = pack_f16(sacc[st][kb4][0], sacc[st][kb4][1]);
                        half2 s23 = pack_f16(sacc[st][kb4][2], sacc[st][kb4][3]);
                        half2 a01 = s01 * c8 + c1;            // fuses to v_pk_fma_f16
                        half2 a23 = s23 * c8 + c1;
                        half2 w01 = a01 * (a01 * ch) + ch;    // 0.5*a^2 + 0.5 = 1 + x + 0.5x^2
                        half2 w23 = a23 * (a23 * ch) + ch;
                        if (nm) {
                            const int i0 = 16 * (4 * wk + 2 * hf + kb4) + 4 * quad;
                            w01[0] = (i0 + 0 <= thr) ? w01[0] : (_Float16)0.f;
                            w01[1] = (i0 + 1 <= thr) ? w01[1] : (_Float16)0.f;
                            w23[0] = (i0 + 2 <= thr) ? w23[0] : (_Float16)0.f;
                            w23[1] = (i0 + 3 <= thr) ? w23[1] : (_Float16)0.f;
                        }
                        wh[kb4][0] = w01;
                        wh[kb4][1] = w23;
                    }
                    half4 lo = __builtin_shufflevector(wh[0][0], wh[0][1], 0, 1, 2, 3);
                    half4 hi = __builtin_shufflevector(wh[1][0], wh[1][1], 0, 1, 2, 3);
                    wf[st] = __builtin_shufflevector(lo, hi, 0, 1, 2, 3, 4, 5, 6, 7);
                }

                // O^T += V^T * W^T (K=32 f16) for this 32-key group; va reused across 4 strips
                #pragma unroll
                for (int db = 0; db < 4; ++db) {
                    half8 va = *(const half8*)&Vc[(16 * db + lm) * LDV + 32 * grp + 8 * quad];
                    #pragma unroll
                    for (int st = 0; st < 4; ++st)
                        oacc[st][db] = __builtin_amdgcn_mfma_f32_16x16x32_f16(va, wf[st], oacc[st][db], 0, 0, 0);
                }
                #pragma unroll
                for (int st = 0; st < 4; ++st)
                    zacc[st] = __builtin_amdgcn_mfma_f32_16x16x32_f16(ones, wf[st], zacc[st], 0, 0, 0);
            }
        }

        asm volatile("s_waitcnt lgkmcnt(0)" ::: "memory");
        __builtin_amdgcn_s_barrier();   // readers done before next iter's DMA overwrites
    }

    // ---- epilogue: per-group cross-wave (wk) reduction through LDS, normalize, store ----
    float* base = (float*)(smem + grpB * TILE_BYTES);   // disjoint per group
    float* Ored = base;                                 // [128][68] f32 = 34816 B
    float* zred = (float*)((char*)base + 34816);        // [128]     f32 =   512 B
    if (wk) {
        #pragma unroll
        for (int st = 0; st < 4; ++st) {
            const int r = wq * 64 + 16 * st + lm;
            #pragma unroll
            for (int db = 0; db < 4; ++db)
                *(floatx4*)&Ored[(size_t)r * 68 + 16 * db + 4 * quad] = oacc[st][db];
            zred[r] = zacc[st][0];
        }
    }
    __syncthreads();
    if (!wk) {
        #pragma unroll
        for (int st = 0; st < 4; ++st) {
            const int r = wq * 64 + 16 * st + lm;
            const float inv = 1.0f / (zacc[st][0] + zred[r] + 1e-6f);
            const int qrow = q0w + 64 * wq + 16 * st + lm;
            float* orow = op + ((size_t)bh * Lc + qrow) * Dc;
            #pragma unroll
            for (int db = 0; db < 4; ++db) {
                floatx4 part = *(const floatx4*)&Ored[(size_t)r * 68 + 16 * db + 4 * quad];
                floatx4 t = (oacc[st][db] + part) * inv;
                *(floatx4*)&orow[16 * db + 4 * quad] = t;
            }
        }
    }
}

extern "C" void kernel_launch(void* const* d_in, const int* in_sizes, int n_in,
                              void* d_out, int out_size, void* d_ws, size_t ws_size,
                              hipStream_t stream) {
    const float* q = (const float*)d_in[0];
    const float* k = (const float*)d_in[1];
    const float* v = (const float*)d_in[2];
    float* o = (float*)d_out;

    char* kv = (char*)d_ws;   // 32 bh x 16 tiles x 35840 B = 18.35 MB

    prep<<<dim3(2048), dim3(256), 0, stream>>>(k, v, kv);
    taylor_attn<<<dim3(BHn * NQT / 2), dim3(512), 0, stream>>>(q, kv, o);
}

// Round 5
// 123.757 us; speedup vs baseline: 1.0379x; 1.0379x over previous
//
#include <hip/hip_runtime.h>
#include <hip/hip_bf16.h>

typedef __bf16    bf16x8  __attribute__((ext_vector_type(8)));
typedef __bf16    bf16x4  __attribute__((ext_vector_type(4)));
typedef _Float16  half8   __attribute__((ext_vector_type(8)));
typedef _Float16  half4   __attribute__((ext_vector_type(4)));
typedef _Float16  half2   __attribute__((ext_vector_type(2)));
typedef float     floatx4 __attribute__((ext_vector_type(4)));

constexpr int Bc  = 2;
constexpr int Hc  = 16;
constexpr int Lc  = 2048;
constexpr int Dc  = 64;
constexpr int BHn = Bc * Hc;     // 32
constexpr int BM  = 64;          // query rows per q-tile
constexpr int BN  = 64;          // keys per kv tile
constexpr int NQT = Lc / BM;     // 32 query tiles
constexpr int LDK = 72;          // K padded stride (bf16) -> row = 144 B (2-way banks, free)
constexpr int LDV = 72;          // V^T padded stride (f16) -> row = 144 B
constexpr int KB_T = BN * LDK * 2;              // 9216
constexpr int VB_T = Dc * LDV * 2;              // 9216
constexpr int TILE_BYTES = KB_T + VB_T;         // 18432 (= LDS image of one tile)
constexpr int TILE_GRANS = TILE_BYTES / 16;     // 1152 granules of 16 B

static __device__ __forceinline__ half2 pack_f16(float a, float b) {
    return __builtin_bit_cast(half2, __builtin_amdgcn_cvt_pkrtz(a, b));
}

static __device__ __forceinline__ void dma16(const void* g, void* l) {
    __builtin_amdgcn_global_load_lds(
        (const __attribute__((address_space(1))) void*)g,
        (__attribute__((address_space(3))) void*)l, 16, 0, 0);
}

// ---- pre-pass: write K/V tiles in the exact padded LDS image ----
// kv layout: [bh][tile=32][ K: 64 rows x 144 B | V^T: 64 d-rows x 144 B ] = 18432 B/tile
// V^T value at [d][pcol] = V[key(pcol)][d]; pcol permutation within each 32-key group:
// k5 -> 8*((k5>>2)&3) + 4*(k5>>4) + (k5&3)  (makes PV A-frags b128-contiguous)
__global__ void prep(const float* __restrict__ kp, const float* __restrict__ vp,
                     char* __restrict__ kv) {
    const int bid = blockIdx.x, tid = threadIdx.x;
    if (bid < 1024) {
        // K part: 1024 blocks x 256 threads; 4 threads per K row (16 d each)
        const int R    = bid * 64 + (tid >> 2);   // global row: bh*2048 + key
        const int s    = tid & 3;
        const int bh   = R >> 11;
        const int key  = R & 2047;
        const int tile = key >> 6;
        const int krow = key & 63;
        const float* src = kp + (size_t)R * 64 + s * 16;
        char* dst = kv + (size_t)(bh * 32 + tile) * TILE_BYTES + krow * 144 + s * 32;
        #pragma unroll
        for (int h = 0; h < 2; ++h) {
            floatx4 a = *(const floatx4*)(src + h * 8);
            floatx4 b = *(const floatx4*)(src + h * 8 + 4);
            bf16x8 o;
            o[0] = (__bf16)a[0]; o[1] = (__bf16)a[1]; o[2] = (__bf16)a[2]; o[3] = (__bf16)a[3];
            o[4] = (__bf16)b[0]; o[5] = (__bf16)b[1]; o[6] = (__bf16)b[2]; o[7] = (__bf16)b[3];
            *(bf16x8*)(dst + h * 16) = o;
        }
    } else {
        // V part: 1024 blocks; block handles one 64-key tile x 64 d
        const int vb   = bid - 1024;
        const int bh   = vb >> 5, kt = vb & 31;   // kt = tile index
        const int key  = kt * 64 + (tid & 63);
        const int kwt  = tid & 63;                // key within tile
        const int k5   = kwt & 31;
        const int pcol = (kwt & 32) | (((k5 >> 2) & 3) * 8 + ((k5 >> 4) & 1) * 4 + (k5 & 3));
        const int d0   = (tid >> 6) * 16;
        const float* src = vp + ((size_t)bh * Lc + key) * Dc;
        _Float16* dst = (_Float16*)(kv + (size_t)(bh * 32 + kt) * TILE_BYTES + KB_T);
        #pragma unroll
        for (int i = 0; i < 16; ++i) {
            const int d = d0 + i;
            dst[(size_t)d * LDV + pcol] = (_Float16)src[d];
        }
    }
}

// ---- main kernel: 1024 blocks (4/CU resident), 256 threads, dbuf DMA, counted vmcnt ----
// 4 waves/block, each wave owns 16 q-rows x all 64 keys (complete z, no reduction).
// qi per 256-block round: {t, 15-t, 16+t, 31-t} -> each CU slot sums to 66 iterations.
__global__ __launch_bounds__(256, 4)
void taylor_attn(const float* __restrict__ qp, const char* __restrict__ kv,
                 float* __restrict__ op)
{
    __shared__ __align__(16) char smem[2 * TILE_BYTES];   // 36864 B: buf0 | buf1

    const int tid  = threadIdx.x;
    const int wv   = tid >> 6;         // wave = q-strip owner (16 rows)
    const int lane = tid & 63;
    const int lm   = lane & 15;
    const int quad = lane >> 4;

    const int rnd = (int)(blockIdx.x >> 8);    // 0..3
    const int s_  = (int)(blockIdx.x & 255);
    const int bh  = s_ & 31;
    const int t_  = s_ >> 5;                   // 0..7
    const int qi  = (rnd == 0) ? t_ : (rnd == 1) ? (15 - t_)
                  : (rnd == 2) ? (16 + t_) : (31 - t_);
    const int q0   = qi * BM;
    const int jmax = qi;

    const char* kvbh = kv + (size_t)bh * 32 * TILE_BYTES;

    // ---- issue Q global loads first (oldest vmem), then tile-0 DMA into buf0 ----
    floatx4 qv[4];
    const int r0 = tid >> 2, s4 = tid & 3;     // r0: 0..63, s4: quarter of the row
    {
        const float* qbase = qp + ((size_t)bh * Lc + q0) * Dc;
        #pragma unroll
        for (int i = 0; i < 4; ++i)
            qv[i] = *(const floatx4*)(qbase + r0 * 64 + s4 * 16 + i * 4);
    }
    {
        #pragma unroll
        for (int rep = 0; rep < 4; ++rep)
            dma16(kvbh + (rep * 256 + tid) * 16, smem + (rep * 256 + tid) * 16);
        if (tid < 128)
            dma16(kvbh + (1024 + tid) * 16, smem + (1024 + tid) * 16);
    }

    // ---- stage Q (fp32 -> bf16) into buf1's K area, extract per-wave B-frags ----
    {
        __bf16* Qs = (__bf16*)(smem + TILE_BYTES);
        #pragma unroll
        for (int i = 0; i < 4; ++i) {
            bf16x4 b;
            b[0] = (__bf16)qv[i][0]; b[1] = (__bf16)qv[i][1];
            b[2] = (__bf16)qv[i][2]; b[3] = (__bf16)qv[i][3];
            *(bf16x4*)&Qs[r0 * LDK + s4 * 16 + i * 4] = b;
        }
    }
    asm volatile("s_waitcnt lgkmcnt(0)" ::: "memory");
    __builtin_amdgcn_s_barrier();

    bf16x8 qa[2];   // [kf]; B-frag: n=lm (qrow), k=kf*32+quad*8+j
    {
        const __bf16* Qs = (const __bf16*)(smem + TILE_BYTES);
        #pragma unroll
        for (int kf = 0; kf < 2; ++kf)
            qa[kf] = *(const bf16x8*)&Qs[(16 * wv + lm) * LDK + kf * 32 + quad * 8];
    }
    asm volatile("s_waitcnt lgkmcnt(0)" ::: "memory");
    __builtin_amdgcn_s_barrier();   // all qa extracted before loop DMA overwrites buf1

    floatx4 oacc[4] = {};     // O^T: [d-block]; col=qrow=lm, row=d=16*db+4*quad+r
    floatx4 zacc    = {};     // z via ones-MFMA: every element = z[qrow=lm]

    const half8 ones = {(_Float16)1.f, (_Float16)1.f, (_Float16)1.f, (_Float16)1.f,
                        (_Float16)1.f, (_Float16)1.f, (_Float16)1.f, (_Float16)1.f};
    const half2 c8  = {(_Float16)0.125f, (_Float16)0.125f};
    const half2 c1  = {(_Float16)1.f,    (_Float16)1.f};
    const half2 ch  = {(_Float16)0.5f,   (_Float16)0.5f};

    for (int j = 0; j <= jmax; ++j) {
        const int cur = j & 1;
        const __bf16*   Kc = (const __bf16*)(smem + cur * TILE_BYTES);
        const _Float16* Vc = (const _Float16*)(smem + cur * TILE_BYTES + KB_T);

        // ---- issue next tile's DMA into the other buffer; counted vmcnt (never 0) ----
        if (j < jmax) {
            const char* src = kvbh + (size_t)(j + 1) * TILE_BYTES;
            char* dst = smem + (cur ^ 1) * TILE_BYTES;
            #pragma unroll
            for (int rep = 0; rep < 4; ++rep)
                dma16(src + (rep * 256 + tid) * 16, dst + (rep * 256 + tid) * 16);
            if (tid < 128)
                dma16(src + (1024 + tid) * 16, dst + (1024 + tid) * 16);
            if (wv < 2) asm volatile("s_waitcnt vmcnt(5)" ::: "memory");
            else        asm volatile("s_waitcnt vmcnt(4)" ::: "memory");
        } else {
            asm volatile("s_waitcnt vmcnt(0)" ::: "memory");
        }
        __builtin_amdgcn_s_barrier();

        // ---- S^T = K * Q^T over all 64 keys (4 kb groups of 16) ----
        floatx4 sacc[4] = {};
        #pragma unroll
        for (int kb = 0; kb < 4; ++kb) {
            #pragma unroll
            for (int kf = 0; kf < 2; ++kf) {
                bf16x8 ka = *(const bf16x8*)&Kc[(16 * kb + lm) * LDK + kf * 32 + quad * 8];
                sacc[kb] = __builtin_amdgcn_mfma_f32_16x16x32_bf16(ka, qa[kf], sacc[kb], 0, 0, 0);
            }
        }

        const bool nm = (j == jmax);           // only the diagonal tile masks
        const int  thr = 16 * wv + lm;         // key threshold (valid when nm)

        // ---- packed-f16 Taylor + causal mask; wf = W B-frags (registers only) ----
        half8 wf[2];
        #pragma unroll
        for (int g = 0; g < 2; ++g) {
            half2 wh[2][2];
            #pragma unroll
            for (int kb4 = 0; kb4 < 2; ++kb4) {
                const int kb = 2 * g + kb4;
                half2 s01 = pack_f16(sacc[kb][0], sacc[kb][1]);
                half2 s23 = pack_f16(sacc[kb][2], sacc[kb][3]);
                half2 a01 = s01 * c8 + c1;            // fuses to v_pk_fma_f16
                half2 a23 = s23 * c8 + c1;
                half2 w01 = a01 * (a01 * ch) + ch;    // 0.5*a^2 + 0.5 = 1 + x + 0.5x^2
                half2 w23 = a23 * (a23 * ch) + ch;
                if (nm) {
                    const int i0 = 16 * kb + 4 * quad;
                    w01[0] = (i0 + 0 <= thr) ? w01[0] : (_Float16)0.f;
                    w01[1] = (i0 + 1 <= thr) ? w01[1] : (_Float16)0.f;
                    w23[0] = (i0 + 2 <= thr) ? w23[0] : (_Float16)0.f;
                    w23[1] = (i0 + 3 <= thr) ? w23[1] : (_Float16)0.f;
                }
                wh[kb4][0] = w01;
                wh[kb4][1] = w23;
            }
            half4 lo = __builtin_shufflevector(wh[0][0], wh[0][1], 0, 1, 2, 3);
            half4 hi = __builtin_shufflevector(wh[1][0], wh[1][1], 0, 1, 2, 3);
            wf[g] = __builtin_shufflevector(lo, hi, 0, 1, 2, 3, 4, 5, 6, 7);
        }

        // ---- O^T += V^T * W^T (K=32 f16) per 32-key group; z via ones-MFMA ----
        #pragma unroll
        for (int db = 0; db < 4; ++db) {
            #pragma unroll
            for (int g = 0; g < 2; ++g) {
                half8 va = *(const half8*)&Vc[(16 * db + lm) * LDV + 32 * g + 8 * quad];
                oacc[db] = __builtin_amdgcn_mfma_f32_16x16x32_f16(va, wf[g], oacc[db], 0, 0, 0);
            }
        }
        #pragma unroll
        for (int g = 0; g < 2; ++g)
            zacc = __builtin_amdgcn_mfma_f32_16x16x32_f16(ones, wf[g], zacc, 0, 0, 0);

        asm volatile("s_waitcnt lgkmcnt(0)" ::: "memory");
        __builtin_amdgcn_s_barrier();   // readers done before next iter's DMA overwrites
    }

    // ---- epilogue: z complete per wave; normalize, store ----
    const float inv = 1.0f / (zacc[0] + 1e-6f);
    const int qrow = q0 + 16 * wv + lm;
    float* orow = op + ((size_t)bh * Lc + qrow) * Dc;
    #pragma unroll
    for (int db = 0; db < 4; ++db) {
        floatx4 t = oacc[db] * inv;
        *(floatx4*)&orow[16 * db + 4 * quad] = t;
    }
}

extern "C" void kernel_launch(void* const* d_in, const int* in_sizes, int n_in,
                              void* d_out, int out_size, void* d_ws, size_t ws_size,
                              hipStream_t stream) {
    const float* q = (const float*)d_in[0];
    const float* k = (const float*)d_in[1];
    const float* v = (const float*)d_in[2];
    float* o = (float*)d_out;

    char* kv = (char*)d_ws;   // 32 bh x 32 tiles x 18432 B = 18.87 MB

    prep<<<dim3(2048), dim3(256), 0, stream>>>(k, v, kv);
    taylor_attn<<<dim3(BHn * NQT), dim3(256), 0, stream>>>(q, kv, o);
}

// Round 6
// 119.349 us; speedup vs baseline: 1.0763x; 1.0369x over previous
//
#include <hip/hip_runtime.h>
#include <hip/hip_bf16.h>

typedef __bf16    bf16x8  __attribute__((ext_vector_type(8)));
typedef __bf16    bf16x4  __attribute__((ext_vector_type(4)));
typedef _Float16  half8   __attribute__((ext_vector_type(8)));
typedef _Float16  half4   __attribute__((ext_vector_type(4)));
typedef _Float16  half2   __attribute__((ext_vector_type(2)));
typedef float     floatx4 __attribute__((ext_vector_type(4)));

constexpr int Bc  = 2;
constexpr int Hc  = 16;
constexpr int Lc  = 2048;
constexpr int Dc  = 64;
constexpr int BHn = Bc * Hc;     // 32
constexpr int BM  = 128;         // query rows per q-tile
constexpr int BN  = 128;         // keys per kv tile
constexpr int NQT = Lc / BM;     // 16 query tiles
constexpr int LDK = 72;          // K padded stride (bf16 elems) -> row = 144 B
constexpr int LDV = 136;         // V^T padded stride (f16 elems) -> row = 272 B
constexpr int LDQ = 72;          // Q staging stride (bf16) in buf1's K area
constexpr int KBYTES = BN * LDK * 2;            // 18432
constexpr int VBYTES = Dc * LDV * 2;            // 17408
constexpr int TILE_BYTES = KBYTES + VBYTES;     // 35840 (= LDS image of one tile)

static __device__ __forceinline__ half2 pack_f16(float a, float b) {
    return __builtin_bit_cast(half2, __builtin_amdgcn_cvt_pkrtz(a, b));
}

static __device__ __forceinline__ void dma16(const void* g, void* l) {
    __builtin_amdgcn_global_load_lds(
        (const __attribute__((address_space(1))) void*)g,
        (__attribute__((address_space(3))) void*)l, 16, 0, 0);
}

// ---- pre-pass: write K/V tiles in the exact padded LDS image ----
// kv layout: [bh][tile=16][ K: 128 rows x 144 B | V^T: 64 rows x 272 B ] = 35840 B/tile
// V^T value at [d][pcol] = V[key(pcol)][d]; pcol permutation within each 32-key group:
// k5 -> 8*((k5>>2)&3) + 4*(k5>>4) + (k5&3)  (makes PV A-frags b128-contiguous)
__global__ void prep(const float* __restrict__ kp, const float* __restrict__ vp,
                     char* __restrict__ kv) {
    const int bid = blockIdx.x, tid = threadIdx.x;
    if (bid < 1024) {
        // K part: 1024 blocks x 256 threads; 4 threads per K row (16 d each)
        const int R    = bid * 64 + (tid >> 2);   // global row: bh*2048 + key
        const int s    = tid & 3;
        const int bh   = R >> 11;
        const int key  = R & 2047;
        const int tile = key >> 7;
        const int krow = key & 127;
        const float* src = kp + (size_t)R * 64 + s * 16;
        char* dst = kv + (size_t)(bh * 16 + tile) * TILE_BYTES + krow * 144 + s * 32;
        #pragma unroll
        for (int h = 0; h < 2; ++h) {
            floatx4 a = *(const floatx4*)(src + h * 8);
            floatx4 b = *(const floatx4*)(src + h * 8 + 4);
            bf16x8 o;
            o[0] = (__bf16)a[0]; o[1] = (__bf16)a[1]; o[2] = (__bf16)a[2]; o[3] = (__bf16)a[3];
            o[4] = (__bf16)b[0]; o[5] = (__bf16)b[1]; o[6] = (__bf16)b[2]; o[7] = (__bf16)b[3];
            *(bf16x8*)(dst + h * 16) = o;
        }
    } else {
        // V part: 1024 blocks; block handles 64 keys (half a tile) x 64 d
        const int vb   = bid - 1024;
        const int bh   = vb >> 5, kt = vb & 31;
        const int key  = kt * 64 + (tid & 63);
        const int tile = kt >> 1;
        const int kwt  = (kt & 1) * 64 + (tid & 63);   // key within tile
        const int k5   = kwt & 31;
        const int pcol = (kwt & ~31) | (((k5 >> 2) & 3) * 8 + ((k5 >> 4) & 1) * 4 + (k5 & 3));
        const int d0   = (tid >> 6) * 16;
        const float* src = vp + ((size_t)bh * Lc + key) * Dc;
        _Float16* dst = (_Float16*)(kv + (size_t)(bh * 16 + tile) * TILE_BYTES + KBYTES);
        #pragma unroll
        for (int i = 0; i < 16; ++i) {
            const int d = d0 + i;
            dst[(size_t)d * LDV + pcol] = (_Float16)src[d];
        }
    }
}

// ---- main kernel: 512 blocks (2/CU), single-barrier-per-iteration dbuf DMA ----
// Per iter: __syncthreads() (drains own tile-j DMA + converges) -> issue DMA j+1
// into the other buffer (safe: all readers of it are past the barrier) -> compute j.
__global__ __launch_bounds__(256, 2)
void taylor_attn(const float* __restrict__ qp, const char* __restrict__ kv,
                 float* __restrict__ op)
{
    __shared__ __align__(16) char smem[2 * TILE_BYTES];   // 71680 B: buf0 | buf1

    const int tid  = threadIdx.x;
    const int wv   = tid >> 6;
    const int lane = tid & 63;
    const int lm   = lane & 15;
    const int quad = lane >> 4;
    const int wq   = wv >> 1;   // q-half owner: rows [64*wq, 64*wq+64)
    const int wk   = wv & 1;    // key-half owner: keys [64*wk, 64*wk+64)

    const int cu    = (int)(blockIdx.x & 255);
    const int snd   = (int)(blockIdx.x >> 8);
    const int bh    = cu & 31;
    const int qslot = cu >> 5;
    const int qi    = snd ? qslot : (NQT - 1 - qslot);   // complement-paired: 17 iters/CU
    const int q0    = qi * BM;
    const int jmax  = qi;

    const float* qbase = qp + ((size_t)bh * Lc + q0) * Dc;
    const char*  kvbh  = kv + (size_t)bh * 16 * TILE_BYTES;

    // ---- issue Q global loads first (oldest vmem), then tile-0 DMA into buf0 ----
    floatx4 qv[8];
    const int r0 = tid >> 4, c4 = tid & 15;
    #pragma unroll
    for (int rep = 0; rep < 8; ++rep)
        qv[rep] = *(const floatx4*)(qbase + (r0 + rep * 16) * Dc + c4 * 4);

    {
        const char* src = kvbh;          // tile 0
        #pragma unroll
        for (int rep = 0; rep < 8; ++rep)
            dma16(src + (rep * 256 + tid) * 16, smem + (rep * 256 + tid) * 16);
        if (tid < 192)
            dma16(src + (2048 + tid) * 16, smem + (2048 + tid) * 16);
    }

    // ---- stage Q (fp32 -> bf16) into buf1's K area, extract per-strip B-frags ----
    {
        __bf16* Qs = (__bf16*)(smem + TILE_BYTES);
        #pragma unroll
        for (int rep = 0; rep < 8; ++rep) {
            bf16x4 b;
            b[0] = (__bf16)qv[rep][0]; b[1] = (__bf16)qv[rep][1];
            b[2] = (__bf16)qv[rep][2]; b[3] = (__bf16)qv[rep][3];
            *(bf16x4*)&Qs[(r0 + rep * 16) * LDQ + c4 * 4] = b;
        }
    }
    __syncthreads();   // Q staged & visible (also covers Q-load drain via ds_write deps)

    bf16x8 qa[4][2];   // [strip][kf]; B-frag: n=lm (qrow), k=kf*32+quad*8+j
    {
        const __bf16* Qs = (const __bf16*)(smem + TILE_BYTES);
        #pragma unroll
        for (int st = 0; st < 4; ++st)
            #pragma unroll
            for (int kf = 0; kf < 2; ++kf)
                qa[st][kf] = *(const bf16x8*)&Qs[(64 * wq + 16 * st + lm) * LDQ + kf * 32 + quad * 8];
    }
    // NOTE: loop-top __syncthreads() (lgkmcnt(0)+barrier) guarantees all waves'
    // qa ds_reads completed before iteration 0 issues the tile-1 DMA into buf1.

    floatx4 oacc[4][4] = {};     // O^T partial (this wave's 64 keys): [strip][d-block]
    floatx4 zacc[4]    = {};     // z partial via ones-MFMA

    const half8 ones = {(_Float16)1.f, (_Float16)1.f, (_Float16)1.f, (_Float16)1.f,
                        (_Float16)1.f, (_Float16)1.f, (_Float16)1.f, (_Float16)1.f};
    const half2 c8  = {(_Float16)0.125f, (_Float16)0.125f};
    const half2 c1  = {(_Float16)1.f,    (_Float16)1.f};
    const half2 ch  = {(_Float16)0.5f,   (_Float16)0.5f};

    for (int j = 0; j <= jmax; ++j) {
        const int cur = j & 1;
        const __bf16*   Kc = (const __bf16*)(smem + cur * TILE_BYTES);
        const _Float16* Vc = (const _Float16*)(smem + cur * TILE_BYTES + KBYTES);

        // ---- single sync point: drain own tile-j DMAs (issued a full compute
        // phase ago -> ~free) and converge all waves past iteration j-1 ----
        __syncthreads();

        // ---- issue next tile's DMA into the other buffer (post-barrier: safe) ----
        if (j < jmax) {
            const char* src = kvbh + (size_t)(j + 1) * TILE_BYTES;
            char* dst = smem + (cur ^ 1) * TILE_BYTES;
            #pragma unroll
            for (int rep = 0; rep < 8; ++rep)
                dma16(src + (rep * 256 + tid) * 16, dst + (rep * 256 + tid) * 16);
            if (tid < 192)
                dma16(src + (2048 + tid) * 16, dst + (2048 + tid) * 16);
        }

        const bool nm = (j == jmax);                 // only the diagonal tile masks
        // ---- two 32-key sub-phases of this wave's 64 keys ----
        #pragma unroll
        for (int hf = 0; hf < 2; ++hf) {
            const int grp = 2 * wk + hf;             // 32-key group within the 128-tile

            // S^T = K * Q^T for key rows [32*grp, 32*grp+32), all 4 q-strips
            floatx4 sacc[4][2] = {};
            __builtin_amdgcn_s_setprio(1);
            #pragma unroll
            for (int kb4 = 0; kb4 < 2; ++kb4) {
                const int row0 = 16 * (4 * wk + 2 * hf + kb4);
                #pragma unroll
                for (int kf = 0; kf < 2; ++kf) {
                    bf16x8 ka = *(const bf16x8*)&Kc[(row0 + lm) * LDK + kf * 32 + quad * 8];
                    #pragma unroll
                    for (int st = 0; st < 4; ++st)
                        sacc[st][kb4] = __builtin_amdgcn_mfma_f32_16x16x32_bf16(ka, qa[st][kf], sacc[st][kb4], 0, 0, 0);
                }
            }
            __builtin_amdgcn_s_setprio(0);

            // packed-f16 Taylor + causal mask; wf = W B-frags (registers only)
            half8 wf[4];
            #pragma unroll
            for (int st = 0; st < 4; ++st) {
                const int thr = q0 + 64 * wq + 16 * st + lm - j * BN;
                half2 wh[2][2];
                #pragma unroll
                for (int kb4 = 0; kb4 < 2; ++kb4) {
                    half2 s01 = pack_f16(sacc[st][kb4][0], sacc[st][kb4][1]);
                    half2 s23 = pack_f16(sacc[st][kb4][2], sacc[st][kb4][3]);
                    half2 a01 = s01 * c8 + c1;            // fuses to v_pk_fma_f16
                    half2 a23 = s23 * c8 + c1;
                    half2 w01 = a01 * (a01 * ch) + ch;    // 0.5*a^2 + 0.5 = 1 + x + 0.5x^2
                    half2 w23 = a23 * (a23 * ch) + ch;
                    if (nm) {
                        const int i0 = 16 * (4 * wk + 2 * hf + kb4) + 4 * quad;
                        w01[0] = (i0 + 0 <= thr) ? w01[0] : (_Float16)0.f;
                        w01[1] = (i0 + 1 <= thr) ? w01[1] : (_Float16)0.f;
                        w23[0] = (i0 + 2 <= thr) ? w23[0] : (_Float16)0.f;
                        w23[1] = (i0 + 3 <= thr) ? w23[1] : (_Float16)0.f;
                    }
                    wh[kb4][0] = w01;
                    wh[kb4][1] = w23;
                }
                half4 lo = __builtin_shufflevector(wh[0][0], wh[0][1], 0, 1, 2, 3);
                half4 hi = __builtin_shufflevector(wh[1][0], wh[1][1], 0, 1, 2, 3);
                wf[st] = __builtin_shufflevector(lo, hi, 0, 1, 2, 3, 4, 5, 6, 7);
            }

            // O^T += V^T * W^T (K=32 f16) for this 32-key group; va reused across 4 strips
            __builtin_amdgcn_s_setprio(1);
            #pragma unroll
            for (int db = 0; db < 4; ++db) {
                half8 va = *(const half8*)&Vc[(16 * db + lm) * LDV + 32 * grp + 8 * quad];
                #pragma unroll
                for (int st = 0; st < 4; ++st)
                    oacc[st][db] = __builtin_amdgcn_mfma_f32_16x16x32_f16(va, wf[st], oacc[st][db], 0, 0, 0);
            }
            #pragma unroll
            for (int st = 0; st < 4; ++st)
                zacc[st] = __builtin_amdgcn_mfma_f32_16x16x32_f16(ones, wf[st], zacc[st], 0, 0, 0);
            __builtin_amdgcn_s_setprio(0);
        }
        // no trailing barrier: next iteration's __syncthreads() provides it
    }

    // ---- epilogue: cross-wave (wk) reduction through LDS, normalize, store ----
    __syncthreads();   // all waves done reading the last tile before smem reuse
    float* Ored = (float*)smem;                     // [128][68] f32 = 34816 B (buf0 area)
    float* zred = (float*)(smem + 34816);           // [128]     f32 =   512 B
    if (wk) {
        #pragma unroll
        for (int st = 0; st < 4; ++st) {
            const int r = wq * 64 + 16 * st + lm;
            #pragma unroll
            for (int db = 0; db < 4; ++db)
                *(floatx4*)&Ored[(size_t)r * 68 + 16 * db + 4 * quad] = oacc[st][db];
            zred[r] = zacc[st][0];
        }
    }
    __syncthreads();
    if (!wk) {
        #pragma unroll
        for (int st = 0; st < 4; ++st) {
            const int r = wq * 64 + 16 * st + lm;
            const float inv = 1.0f / (zacc[st][0] + zred[r] + 1e-6f);
            const int qrow = q0 + 64 * wq + 16 * st + lm;
            float* orow = op + ((size_t)bh * Lc + qrow) * Dc;
            #pragma unroll
            for (int db = 0; db < 4; ++db) {
                floatx4 part = *(const floatx4*)&Ored[(size_t)r * 68 + 16 * db + 4 * quad];
                floatx4 t = (oacc[st][db] + part) * inv;
                *(floatx4*)&orow[16 * db + 4 * quad] = t;
            }
        }
    }
}

extern "C" void kernel_launch(void* const* d_in, const int* in_sizes, int n_in,
                              void* d_out, int out_size, void* d_ws, size_t ws_size,
                              hipStream_t stream) {
    const float* q = (const float*)d_in[0];
    const float* k = (const float*)d_in[1];
    const float* v = (const float*)d_in[2];
    float* o = (float*)d_out;

    char* kv = (char*)d_ws;   // 32 bh x 16 tiles x 35840 B = 18.35 MB

    prep<<<dim3(2048), dim3(256), 0, stream>>>(k, v, kv);
    taylor_attn<<<dim3(NQT * BHn), dim3(256), 0, stream>>>(q, kv, o);
}